// Round 4
// baseline (434.342 us; speedup 1.0000x reference)
//
#include <hip/hip_runtime.h>

// GAT on MI355X. Pipeline (5 dispatches + 1 memset):
//  M0 memset       : cnt = 0, ypart = 0 (single hipMemsetAsync)
//  K1 gemm_att_hist: xh_bf = bf16(x @ lin_w.T)  [8192,256] 64x64 tiled.
//                    FUSED: a_src/a_dst dots from f32 accumulators (8-lane
//                    shuffles) + degree histogram (hides under GEMM).
//  K2 scan         : rowptr = exclusive prefix(cnt + 1/self-loop); wpos copy.
//                    Wave-shuffle scan, 2 barriers.
//  K3 scatter      : CSR bucket ONLY (csr[pos]=src). Per-edge weights are NOT
//                    materialized anymore (w8 deleted: -8.6MB scattered RMW
//                    writes; weight recomputed bit-identically in K4 from
//                    a_src gather + block-uniform a_dst).
//  K4 agg_dot      : fused gather-aggregate + out_w dot (268 MB nt stream).
//                    Weight computed inline; predicated unroll-8 (no serial
//                    tail). Bucketed atomics into ypart[256][32].
//  K5 finalize     : reduce ypart + bias + softmax -> d_out[32]

namespace {
constexpr int  kN    = 8192;
constexpr int  kE    = 262144;
constexpr int  kTotE = kE + kN;          // 270336 (self loops appended)
constexpr long kK    = 2097152;          // N * H * C
constexpr int  kYB   = 256;              // ypart buckets
}

typedef float vfloat4 __attribute__((ext_vector_type(4)));  // native vec for nt loads

static __device__ __forceinline__ ushort f2bf(float f) {  // RNE f32->bf16
  unsigned u = __float_as_uint(f);
  return (ushort)((u + 0x7FFFu + ((u >> 16) & 1u)) >> 16);
}
static __device__ __forceinline__ float bf2f(ushort b) {
  return __uint_as_float(((unsigned)b) << 16);
}

// ------- K1: xh_bf = bf16(x @ lin_w^T) + attention dots + degree histogram -------
// grid (128,4): rowBase = bx*64, colBase = by*64 (cols 64 = heads 2*by, 2*by+1)
__global__ __launch_bounds__(256) void gemm_att_hist(const float* __restrict__ x,
                                                     const float* __restrict__ lw,
                                                     const float* __restrict__ att_s,
                                                     const float* __restrict__ att_d,
                                                     const int* __restrict__ ei,
                                                     ushort* __restrict__ xh_bf,
                                                     float* __restrict__ a_src,
                                                     float* __restrict__ a_dst,
                                                     int* __restrict__ cnt) {
  __shared__ float As[16][68];
  __shared__ float Bs[16][68];
  const int t  = threadIdx.x;
  const int tx = t & 15, ty = t >> 4;
  const int rowBase = blockIdx.x * 64;
  const int colBase = blockIdx.y * 64;
  const int lr = t >> 2;
  const int lk = (t & 3) * 4;

  // degree histogram: 512 edges per block, fire-and-forget, hides under GEMM
  {
    const int bid = blockIdx.y * 128 + blockIdx.x;      // 0..511
    const int gid = bid * 512 + t;
    atomicAdd(&cnt[ei[kE + gid]], 1);                   // ei[1][e] = dst
    atomicAdd(&cnt[ei[kE + gid + 256]], 1);
  }

  float acc[4][4] = {};
  for (int kc = 0; kc < 256; kc += 16) {
    float4 av = *(const float4*)(x  + (long)(rowBase + lr) * 256 + kc + lk);
    float4 bv = *(const float4*)(lw + (long)(colBase + lr) * 256 + kc + lk);
    __syncthreads();
    As[lk + 0][lr] = av.x; As[lk + 1][lr] = av.y; As[lk + 2][lr] = av.z; As[lk + 3][lr] = av.w;
    Bs[lk + 0][lr] = bv.x; Bs[lk + 1][lr] = bv.y; Bs[lk + 2][lr] = bv.z; Bs[lk + 3][lr] = bv.w;
    __syncthreads();
#pragma unroll
    for (int k = 0; k < 16; k++) {
      float4 a4 = *(const float4*)(&As[k][ty * 4]);
      float4 b4 = *(const float4*)(&Bs[k][tx * 4]);
      float aa[4] = {a4.x, a4.y, a4.z, a4.w};
      float bb[4] = {b4.x, b4.y, b4.z, b4.w};
#pragma unroll
      for (int i = 0; i < 4; i++)
#pragma unroll
        for (int j = 0; j < 4; j++) acc[i][j] += aa[i] * bb[j];
    }
  }

  // epilogue A: bf16 store of this thread's 4x4 tile
#pragma unroll
  for (int i = 0; i < 4; i++) {
    const long row = rowBase + ty * 4 + i;
    ushort4 ob = make_ushort4(f2bf(acc[i][0]), f2bf(acc[i][1]),
                              f2bf(acc[i][2]), f2bf(acc[i][3]));
    *(ushort4*)(xh_bf + row * 256 + colBase + tx * 4) = ob;
  }

  // epilogue B: attention dots from the f32 accumulators (8-lane shuffle groups)
  float4 as4 = *(const float4*)(att_s + colBase + tx * 4);
  float4 ad4 = *(const float4*)(att_d + colBase + tx * 4);
#pragma unroll
  for (int i = 0; i < 4; i++) {
    float s = acc[i][0] * as4.x + acc[i][1] * as4.y + acc[i][2] * as4.z + acc[i][3] * as4.w;
    float d = acc[i][0] * ad4.x + acc[i][1] * ad4.y + acc[i][2] * ad4.z + acc[i][3] * ad4.w;
#pragma unroll
    for (int off = 4; off; off >>= 1) {
      s += __shfl_down(s, off, 8);
      d += __shfl_down(d, off, 8);
    }
    if ((tx & 7) == 0) {
      const int row  = rowBase + ty * 4 + i;
      const int head = blockIdx.y * 2 + (tx >> 3);
      a_src[row * 8 + head] = s;
      a_dst[row * 8 + head] = d;
    }
  }
}

// ---------------- K2: single-block exclusive scan (+1 self-loop each) ----------------
// wave-shuffle scan: 16 waves x 64 lanes x 8 elems, 2 barriers total
__global__ __launch_bounds__(1024) void scan_cnt(const int* __restrict__ cnt,
                                                 int* __restrict__ rowptr,
                                                 int* __restrict__ wpos) {
  __shared__ int wsum[16];
  const int t = threadIdx.x, lane = t & 63, w = t >> 6;
  int v[8]; int sum = 0;
#pragma unroll
  for (int q = 0; q < 8; q++) { v[q] = cnt[t * 8 + q] + 1; sum += v[q]; }  // +1 self-loop
  int sc = sum;                                  // inclusive wave scan
#pragma unroll
  for (int off = 1; off < 64; off <<= 1) {
    int n = __shfl_up(sc, off, 64);
    if (lane >= off) sc += n;
  }
  if (lane == 63) wsum[w] = sc;
  __syncthreads();
  if (t < 16) {                                   // scan the 16 wave totals
    int ws = wsum[t];
#pragma unroll
    for (int off = 1; off < 16; off <<= 1) {
      int n = __shfl_up(ws, off, 16);
      if ((t & 15) >= off) ws += n;
    }
    wsum[t] = ws;
  }
  __syncthreads();
  int excl = (w ? wsum[w - 1] : 0) + sc - sum;
#pragma unroll
  for (int q = 0; q < 8; q++) {
    rowptr[t * 8 + q] = excl;
    wpos[t * 8 + q]   = excl;
    excl += v[q];
  }
  if (t == 1023) rowptr[kN] = excl;               // grand total
}

// ---------------- K3: bucket edges by dst (csr only, no weights) ----------------
__global__ __launch_bounds__(256) void scatter_csr(const int* __restrict__ ei,
                                                   int* __restrict__ wpos,
                                                   int* __restrict__ csr) {
  int idx = blockIdx.x * 256 + threadIdx.x;
  if (idx >= kTotE) return;
  int s, d;
  if (idx < kE) { s = ei[idx]; d = ei[kE + idx]; }
  else          { s = idx - kE; d = s; }
  int pos = atomicAdd(&wpos[d], 1);
  csr[pos] = s;
}

// ---------- K4: fused weighted-gather aggregation + final dot ----------
// Block = dst node i. Phase 0 issues the 8 nt out_w loads (independent of the
// gather). Phase 1 gathers bf16 rows + a_src, computes weights inline
// (bit-identical to the old w8 path), predicated unroll-8 (no serial tail).
// Phase 2 exchanges the of-row via LDS, 32 channel dots, bucketed atomics.
__global__ __launch_bounds__(256) void agg_dot(const ushort* __restrict__ xb,
                                               const float* __restrict__ a_src,
                                               const float* __restrict__ a_dst,
                                               const int* __restrict__ rowptr,
                                               const int* __restrict__ csr,
                                               const float* __restrict__ bias,
                                               const float* __restrict__ w,
                                               float* __restrict__ ypart) {
  const int i = blockIdx.x, t = threadIdx.x, h = t >> 5;
  const int lane = t & 63, wid = t >> 6;

  const int beg = rowptr[i], end = rowptr[i + 1];

  // phase 0: prefetch this node's out_w slice — w[c][i*256 + lane*4], c = cc*4+wid
  const long wbase = (long)i * 256 + lane * 4;
  vfloat4 wv[8];
#pragma unroll
  for (int cc = 0; cc < 8; cc++) {
    const int c = cc * 4 + wid;
    wv[cc] = __builtin_nontemporal_load((const vfloat4*)(w + (long)c * kK + wbase));
  }

  const float adh = a_dst[i * 8 + h];   // block-uniform per head

  // phase 1: gather aggregation, predicated unroll x8
  float acc = 0.f, den = 0.f;
  for (int j = beg; j < end; j += 8) {
    const int lim = end - j;            // >= 1
    int s[8];
#pragma unroll
    for (int q = 0; q < 8; q++) s[q] = csr[(q < lim) ? j + q : j];
    float as[8];
#pragma unroll
    for (int q = 0; q < 8; q++) as[q] = a_src[(long)s[q] * 8 + h];
    float f[8];
#pragma unroll
    for (int q = 0; q < 8; q++) f[q] = bf2f(xb[(long)s[q] * 256 + t]);
#pragma unroll
    for (int q = 0; q < 8; q++) {
      float e  = as[q] + adh;
      float ee = (e > 0.f) ? e : 0.2f * e;        // leaky_relu(0.2)
      float wq = (q < lim) ? __expf(ee) : 0.f;    // |e| <~ 5, no max-sub needed
      den += wq;
      acc += wq * f[q];
    }
  }

  // phase 2: of-row through LDS, 32 per-block dots, wave reduce, bucket atomics
  __shared__ float ofs[256];
  __shared__ float yb[32];
  ofs[t] = acc / den + bias[t];
  __syncthreads();
  float4 f4 = *(const float4*)(ofs + lane * 4);
#pragma unroll
  for (int cc = 0; cc < 8; cc++) {
    float p = wv[cc].x * f4.x + wv[cc].y * f4.y + wv[cc].z * f4.z + wv[cc].w * f4.w;
    p += __shfl_down(p, 32, 64);
    p += __shfl_down(p, 16, 64);
    p += __shfl_down(p, 8, 64);
    p += __shfl_down(p, 4, 64);
    p += __shfl_down(p, 2, 64);
    p += __shfl_down(p, 1, 64);
    if (lane == 0) yb[cc * 4 + wid] = p;
  }
  __syncthreads();
  if (t < 32) atomicAdd(&ypart[(i & (kYB - 1)) * 32 + t], yb[t]);
}

// ---------------- K5: reduce ypart[256][32] + bias + softmax ----------------
__global__ __launch_bounds__(1024) void finalize(const float* __restrict__ ypart,
                                                 const float* __restrict__ ob,
                                                 float* __restrict__ out) {
  __shared__ float s[32][33];
  const int t = threadIdx.x;
  const int c = t & 31, r = t >> 5;
  float sum = 0.f;
  for (int q = r; q < kYB; q += 32) sum += ypart[q * 32 + c];  // 8 adds per thread
  s[c][r] = sum;
  __syncthreads();
  if (t < 32) {
    float y = ob[t];
#pragma unroll
    for (int r2 = 0; r2 < 32; r2++) y += s[t][r2];
    float m = y;
#pragma unroll
    for (int off = 16; off; off >>= 1) m = fmaxf(m, __shfl_xor(m, off, 32));
    float e = __expf(y - m);
    float d = e;
#pragma unroll
    for (int off = 16; off; off >>= 1) d += __shfl_xor(d, off, 32);
    out[t] = e / d;
  }
}

extern "C" void kernel_launch(void* const* d_in, const int* in_sizes, int n_in,
                              void* d_out, int out_size, void* d_ws, size_t ws_size,
                              hipStream_t stream) {
  (void)in_sizes; (void)n_in; (void)out_size; (void)ws_size;
  const float* x     = (const float*)d_in[0];
  const int*   ei    = (const int*)  d_in[1];
  const float* lin_w = (const float*)d_in[2];
  const float* att_s = (const float*)d_in[3];
  const float* att_d = (const float*)d_in[4];
  const float* bias  = (const float*)d_in[5];
  const float* out_w = (const float*)d_in[6];
  const float* out_b = (const float*)d_in[7];
  float* out = (float*)d_out;

  // workspace layout (~6 MB; w8 deleted)
  float*  a_src    = (float*)d_ws;
  float*  a_dst    = a_src + kN * 8;
  ushort* xh_bf    = (ushort*)(a_dst + kN * 8);
  int*    cnt      = (int*)(xh_bf + kK);
  float*  ypart    = (float*)(cnt + kN);          // kYB*32 floats, adjacent to cnt
  int*    rowptr   = (int*)(ypart + kYB * 32);
  int*    wpos     = rowptr + (kN + 1);
  int*    csr      = wpos + kN;

  // zero cnt + ypart in one memset (adjacent)
  (void)hipMemsetAsync(cnt, 0, kN * sizeof(int) + kYB * 32 * sizeof(float), stream);
  gemm_att_hist<<<dim3(128, 4), 256, 0, stream>>>(x, lin_w, att_s, att_d, ei,
                                                  xh_bf, a_src, a_dst, cnt);
  scan_cnt   <<<1, 1024, 0, stream>>>(cnt, rowptr, wpos);
  scatter_csr<<<(kTotE + 255) / 256, 256, 0, stream>>>(ei, wpos, csr);
  agg_dot    <<<kN, 256, 0, stream>>>(xh_bf, a_src, a_dst, rowptr, csr, bias,
                                      out_w, ypart);
  finalize   <<<1, 1024, 0, stream>>>(ypart, out_b, out);
}

// Round 5
// 426.102 us; speedup vs baseline: 1.0193x; 1.0193x over previous
//
#include <hip/hip_runtime.h>

// GAT on MI355X. Pipeline (5 dispatches + 1 memset):
//  M0 memset       : cnt = 0, ypart = 0 (single hipMemsetAsync)
//  K1 gemm_att_hist: xh_bf = bf16(x @ lin_w.T)  [8192,256] 64x64 tiled.
//                    FUSED: a_src/a_dst dots from f32 accumulators (8-lane
//                    shuffles) + degree histogram (hides under GEMM).
//  K2 scan         : rowptr = exclusive prefix(cnt + 1/self-loop); wpos copy.
//  K3 scatter      : CSR bucket edges (+self loops) by dst + per-edge 8-head
//                    exp(leakyrelu) weights. (R4 lesson: weights MUST be
//                    computed here, once per edge — recomputing in K4
//                    replicates the exp 32x per edge = +5us VALU.)
//  K4 agg_dot      : fused gather-aggregate + out_w dot (268 MB nt stream).
//                    Predicated unroll-8 (no serial tail). Bucketed atomics
//                    into ypart[256][32].
//  K5 finalize     : reduce ypart + bias + softmax -> d_out[32]

namespace {
constexpr int  kN    = 8192;
constexpr int  kE    = 262144;
constexpr int  kTotE = kE + kN;          // 270336 (self loops appended)
constexpr long kK    = 2097152;          // N * H * C
constexpr int  kYB   = 256;              // ypart buckets
}

typedef float vfloat4 __attribute__((ext_vector_type(4)));  // native vec for nt loads

static __device__ __forceinline__ ushort f2bf(float f) {  // RNE f32->bf16
  unsigned u = __float_as_uint(f);
  return (ushort)((u + 0x7FFFu + ((u >> 16) & 1u)) >> 16);
}
static __device__ __forceinline__ float bf2f(ushort b) {
  return __uint_as_float(((unsigned)b) << 16);
}

// ------- K1: xh_bf = bf16(x @ lin_w^T) + attention dots + degree histogram -------
// grid (128,4): rowBase = bx*64, colBase = by*64 (cols 64 = heads 2*by, 2*by+1)
__global__ __launch_bounds__(256) void gemm_att_hist(const float* __restrict__ x,
                                                     const float* __restrict__ lw,
                                                     const float* __restrict__ att_s,
                                                     const float* __restrict__ att_d,
                                                     const int* __restrict__ ei,
                                                     ushort* __restrict__ xh_bf,
                                                     float* __restrict__ a_src,
                                                     float* __restrict__ a_dst,
                                                     int* __restrict__ cnt) {
  __shared__ float As[16][68];
  __shared__ float Bs[16][68];
  const int t  = threadIdx.x;
  const int tx = t & 15, ty = t >> 4;
  const int rowBase = blockIdx.x * 64;
  const int colBase = blockIdx.y * 64;
  const int lr = t >> 2;
  const int lk = (t & 3) * 4;

  // degree histogram: 512 edges per block, fire-and-forget, hides under GEMM
  {
    const int bid = blockIdx.y * 128 + blockIdx.x;      // 0..511
    const int gid = bid * 512 + t;
    atomicAdd(&cnt[ei[kE + gid]], 1);                   // ei[1][e] = dst
    atomicAdd(&cnt[ei[kE + gid + 256]], 1);
  }

  float acc[4][4] = {};
  for (int kc = 0; kc < 256; kc += 16) {
    float4 av = *(const float4*)(x  + (long)(rowBase + lr) * 256 + kc + lk);
    float4 bv = *(const float4*)(lw + (long)(colBase + lr) * 256 + kc + lk);
    __syncthreads();
    As[lk + 0][lr] = av.x; As[lk + 1][lr] = av.y; As[lk + 2][lr] = av.z; As[lk + 3][lr] = av.w;
    Bs[lk + 0][lr] = bv.x; Bs[lk + 1][lr] = bv.y; Bs[lk + 2][lr] = bv.z; Bs[lk + 3][lr] = bv.w;
    __syncthreads();
#pragma unroll
    for (int k = 0; k < 16; k++) {
      float4 a4 = *(const float4*)(&As[k][ty * 4]);
      float4 b4 = *(const float4*)(&Bs[k][tx * 4]);
      float aa[4] = {a4.x, a4.y, a4.z, a4.w};
      float bb[4] = {b4.x, b4.y, b4.z, b4.w};
#pragma unroll
      for (int i = 0; i < 4; i++)
#pragma unroll
        for (int j = 0; j < 4; j++) acc[i][j] += aa[i] * bb[j];
    }
  }

  // epilogue A: bf16 store of this thread's 4x4 tile
#pragma unroll
  for (int i = 0; i < 4; i++) {
    const long row = rowBase + ty * 4 + i;
    ushort4 ob = make_ushort4(f2bf(acc[i][0]), f2bf(acc[i][1]),
                              f2bf(acc[i][2]), f2bf(acc[i][3]));
    *(ushort4*)(xh_bf + row * 256 + colBase + tx * 4) = ob;
  }

  // epilogue B: attention dots from the f32 accumulators (8-lane shuffle groups)
  float4 as4 = *(const float4*)(att_s + colBase + tx * 4);
  float4 ad4 = *(const float4*)(att_d + colBase + tx * 4);
#pragma unroll
  for (int i = 0; i < 4; i++) {
    float s = acc[i][0] * as4.x + acc[i][1] * as4.y + acc[i][2] * as4.z + acc[i][3] * as4.w;
    float d = acc[i][0] * ad4.x + acc[i][1] * ad4.y + acc[i][2] * ad4.z + acc[i][3] * ad4.w;
#pragma unroll
    for (int off = 4; off; off >>= 1) {
      s += __shfl_down(s, off, 8);
      d += __shfl_down(d, off, 8);
    }
    if ((tx & 7) == 0) {
      const int row  = rowBase + ty * 4 + i;
      const int head = blockIdx.y * 2 + (tx >> 3);
      a_src[row * 8 + head] = s;
      a_dst[row * 8 + head] = d;
    }
  }
}

// ---------------- K2: single-block exclusive scan (+1 self-loop each) ----------------
// wave-shuffle scan: 16 waves x 64 lanes x 8 elems, 2 barriers total
__global__ __launch_bounds__(1024) void scan_cnt(const int* __restrict__ cnt,
                                                 int* __restrict__ rowptr,
                                                 int* __restrict__ wpos) {
  __shared__ int wsum[16];
  const int t = threadIdx.x, lane = t & 63, w = t >> 6;
  int v[8]; int sum = 0;
#pragma unroll
  for (int q = 0; q < 8; q++) { v[q] = cnt[t * 8 + q] + 1; sum += v[q]; }  // +1 self-loop
  int sc = sum;                                  // inclusive wave scan
#pragma unroll
  for (int off = 1; off < 64; off <<= 1) {
    int n = __shfl_up(sc, off, 64);
    if (lane >= off) sc += n;
  }
  if (lane == 63) wsum[w] = sc;
  __syncthreads();
  if (t < 16) {                                   // scan the 16 wave totals
    int ws = wsum[t];
#pragma unroll
    for (int off = 1; off < 16; off <<= 1) {
      int n = __shfl_up(ws, off, 16);
      if ((t & 15) >= off) ws += n;
    }
    wsum[t] = ws;
  }
  __syncthreads();
  int excl = (w ? wsum[w - 1] : 0) + sc - sum;
#pragma unroll
  for (int q = 0; q < 8; q++) {
    rowptr[t * 8 + q] = excl;
    wpos[t * 8 + q]   = excl;
    excl += v[q];
  }
  if (t == 1023) rowptr[kN] = excl;               // grand total
}

// ---------------- K3: bucket edges by dst + per-edge 8-head weights ----------------
__global__ __launch_bounds__(256) void scatter_csr(const int* __restrict__ ei,
                                                   const float* __restrict__ a_src,
                                                   const float* __restrict__ a_dst,
                                                   int* __restrict__ wpos,
                                                   int* __restrict__ csr,
                                                   float* __restrict__ w8) {
  int idx = blockIdx.x * 256 + threadIdx.x;
  if (idx >= kTotE) return;
  int s, d;
  if (idx < kE) { s = ei[idx]; d = ei[kE + idx]; }
  else          { s = idx - kE; d = s; }
  int pos = atomicAdd(&wpos[d], 1);
  csr[pos] = s;
  float4 s0 = *(const float4*)(a_src + s * 8);
  float4 s1 = *(const float4*)(a_src + s * 8 + 4);
  float4 d0 = *(const float4*)(a_dst + d * 8);
  float4 d1 = *(const float4*)(a_dst + d * 8 + 4);
  float e[8] = {s0.x + d0.x, s0.y + d0.y, s0.z + d0.z, s0.w + d0.w,
                s1.x + d1.x, s1.y + d1.y, s1.z + d1.z, s1.w + d1.w};
  float w[8];
#pragma unroll
  for (int h = 0; h < 8; h++) {
    float ee = (e[h] > 0.f) ? e[h] : 0.2f * e[h];   // leaky_relu(0.2)
    w[h] = __expf(ee);                              // |e| <~ 5, no max-sub needed
  }
  float4* wp = (float4*)(w8 + (long)pos * 8);
  wp[0] = make_float4(w[0], w[1], w[2], w[3]);
  wp[1] = make_float4(w[4], w[5], w[6], w[7]);
}

// ---------- K4: fused weighted-gather aggregation + final dot ----------
// Block = dst node i. Phase 0 issues the 8 nt out_w loads (independent of the
// gather). Phase 1 gathers bf16 rows + w8, predicated unroll-8 (no serial
// tail; OOB lanes re-read edge j with weight zero-selected). Phase 2 exchanges
// the of-row via LDS, 32 channel dots, bucketed atomics into ypart.
__global__ __launch_bounds__(256) void agg_dot(const ushort* __restrict__ xb,
                                               const float* __restrict__ w8,
                                               const int* __restrict__ rowptr,
                                               const int* __restrict__ csr,
                                               const float* __restrict__ bias,
                                               const float* __restrict__ w,
                                               float* __restrict__ ypart) {
  const int i = blockIdx.x, t = threadIdx.x, h = t >> 5;
  const int lane = t & 63, wid = t >> 6;

  const int beg = rowptr[i], end = rowptr[i + 1];

  // phase 0: prefetch this node's out_w slice — w[c][i*256 + lane*4], c = cc*4+wid
  const long wbase = (long)i * 256 + lane * 4;
  vfloat4 wv[8];
#pragma unroll
  for (int cc = 0; cc < 8; cc++) {
    const int c = cc * 4 + wid;
    wv[cc] = __builtin_nontemporal_load((const vfloat4*)(w + (long)c * kK + wbase));
  }

  // phase 1: gather aggregation, predicated unroll x8
  float acc = 0.f, den = 0.f;
  for (int j = beg; j < end; j += 8) {
    const int lim = end - j;            // >= 1
    int s[8]; float ww[8]; float f[8];
#pragma unroll
    for (int q = 0; q < 8; q++) {
      const int jj = (q < lim) ? j + q : j;
      s[q]  = csr[jj];
      ww[q] = w8[(long)jj * 8 + h];
    }
#pragma unroll
    for (int q = 0; q < 8; q++) f[q] = bf2f(xb[(long)s[q] * 256 + t]);
#pragma unroll
    for (int q = 0; q < 8; q++) {
      const float wq = (q < lim) ? ww[q] : 0.f;
      den += wq;
      acc += wq * f[q];
    }
  }

  // phase 2: of-row through LDS, 32 per-block dots, wave reduce, bucket atomics
  __shared__ float ofs[256];
  __shared__ float yb[32];
  ofs[t] = acc / den + bias[t];
  __syncthreads();
  float4 f4 = *(const float4*)(ofs + lane * 4);
#pragma unroll
  for (int cc = 0; cc < 8; cc++) {
    float p = wv[cc].x * f4.x + wv[cc].y * f4.y + wv[cc].z * f4.z + wv[cc].w * f4.w;
    p += __shfl_down(p, 32, 64);
    p += __shfl_down(p, 16, 64);
    p += __shfl_down(p, 8, 64);
    p += __shfl_down(p, 4, 64);
    p += __shfl_down(p, 2, 64);
    p += __shfl_down(p, 1, 64);
    if (lane == 0) yb[cc * 4 + wid] = p;
  }
  __syncthreads();
  if (t < 32) atomicAdd(&ypart[(i & (kYB - 1)) * 32 + t], yb[t]);
}

// ---------------- K5: reduce ypart[256][32] + bias + softmax ----------------
__global__ __launch_bounds__(1024) void finalize(const float* __restrict__ ypart,
                                                 const float* __restrict__ ob,
                                                 float* __restrict__ out) {
  __shared__ float s[32][33];
  const int t = threadIdx.x;
  const int c = t & 31, r = t >> 5;
  float sum = 0.f;
  for (int q = r; q < kYB; q += 32) sum += ypart[q * 32 + c];  // 8 adds per thread
  s[c][r] = sum;
  __syncthreads();
  if (t < 32) {
    float y = ob[t];
#pragma unroll
    for (int r2 = 0; r2 < 32; r2++) y += s[t][r2];
    float m = y;
#pragma unroll
    for (int off = 16; off; off >>= 1) m = fmaxf(m, __shfl_xor(m, off, 32));
    float e = __expf(y - m);
    float d = e;
#pragma unroll
    for (int off = 16; off; off >>= 1) d += __shfl_xor(d, off, 32);
    out[t] = e / d;
  }
}

extern "C" void kernel_launch(void* const* d_in, const int* in_sizes, int n_in,
                              void* d_out, int out_size, void* d_ws, size_t ws_size,
                              hipStream_t stream) {
  (void)in_sizes; (void)n_in; (void)out_size; (void)ws_size;
  const float* x     = (const float*)d_in[0];
  const int*   ei    = (const int*)  d_in[1];
  const float* lin_w = (const float*)d_in[2];
  const float* att_s = (const float*)d_in[3];
  const float* att_d = (const float*)d_in[4];
  const float* bias  = (const float*)d_in[5];
  const float* out_w = (const float*)d_in[6];
  const float* out_b = (const float*)d_in[7];
  float* out = (float*)d_out;

  // workspace layout (~15 MB)
  float*  a_src    = (float*)d_ws;
  float*  a_dst    = a_src + kN * 8;
  float*  w8       = a_dst + kN * 8;
  ushort* xh_bf    = (ushort*)(w8 + (long)kTotE * 8);
  int*    cnt      = (int*)(xh_bf + kK);
  float*  ypart    = (float*)(cnt + kN);          // kYB*32 floats, adjacent to cnt
  int*    rowptr   = (int*)(ypart + kYB * 32);
  int*    wpos     = rowptr + (kN + 1);
  int*    csr      = wpos + kN;

  // zero cnt + ypart in one memset (adjacent)
  (void)hipMemsetAsync(cnt, 0, kN * sizeof(int) + kYB * 32 * sizeof(float), stream);
  gemm_att_hist<<<dim3(128, 4), 256, 0, stream>>>(x, lin_w, att_s, att_d, ei,
                                                  xh_bf, a_src, a_dst, cnt);
  scan_cnt   <<<1, 1024, 0, stream>>>(cnt, rowptr, wpos);
  scatter_csr<<<(kTotE + 255) / 256, 256, 0, stream>>>(ei, a_src, a_dst, wpos, csr, w8);
  agg_dot    <<<kN, 256, 0, stream>>>(xh_bf, w8, rowptr, csr, bias, out_w, ypart);
  finalize   <<<1, 1024, 0, stream>>>(ypart, out_b, out);
}

// Round 6
// 415.786 us; speedup vs baseline: 1.0446x; 1.0248x over previous
//
#include <hip/hip_runtime.h>

// GAT on MI355X. Pipeline (5 dispatches + 1 memset):
//  M0 memset       : cnt = 0, ypart = 0 (single hipMemsetAsync)
//  K1 gemm_att_hist: xh_bf = bf16(x @ lin_w.T)  [8192,256] via MFMA
//                    16x16x32 bf16 with hi/lo split of BOTH operands
//                    (3 MFMAs: hh + lh + hl -> f32-exact to ~1e-5 rel;
//                    absmax preserved). D routed through LDS back into the
//                    proven scalar epilogue layout (bf16 store + attention
//                    dots + 8-lane shuffles). Degree histogram fused.
//  K2 scan         : rowptr = exclusive prefix(cnt + 1/self-loop); wpos copy.
//  K3 scatter      : CSR bucket edges (+self loops) by dst + per-edge 8-head
//                    exp(leakyrelu) weights. (R4 lesson: weights computed
//                    here once per edge; recomputing in K4 = 32x VALU.)
//  K4 agg_dot      : fused gather-aggregate + out_w dot (268 MB nt stream).
//                    Predicated unroll-8. Bucketed atomics into ypart[256][32].
//  K5 finalize     : reduce ypart + bias + softmax -> d_out[32]

namespace {
constexpr int  kN    = 8192;
constexpr int  kE    = 262144;
constexpr int  kTotE = kE + kN;          // 270336 (self loops appended)
constexpr long kK    = 2097152;          // N * H * C
constexpr int  kYB   = 256;              // ypart buckets
}

typedef float vfloat4 __attribute__((ext_vector_type(4)));  // native vec for nt loads
typedef short bf16x8  __attribute__((ext_vector_type(8)));  // MFMA A/B frag (4 VGPR)
typedef float f32x4   __attribute__((ext_vector_type(4)));  // MFMA C/D frag

static __device__ __forceinline__ ushort f2bf(float f) {  // RNE f32->bf16
  unsigned u = __float_as_uint(f);
  return (ushort)((u + 0x7FFFu + ((u >> 16) & 1u)) >> 16);
}
static __device__ __forceinline__ float bf2f(ushort b) {
  return __uint_as_float(((unsigned)b) << 16);
}
static __device__ __forceinline__ void bfsplit(float f, ushort& h, ushort& l) {
  h = f2bf(f);
  l = f2bf(f - bf2f(h));   // residual; combined rel err ~1.6e-5
}

// ------- K1: xh_bf = bf16(x @ lin_w^T) + attention dots + degree histogram -------
// grid (128,4): rowBase = bx*64, colBase = by*64 (cols 64 = heads 2*by, 2*by+1)
// MFMA 16x16x32 bf16, hi/lo split both operands. K staged in halves of 128.
// LDS: AB[4][64][136] = {A_hi, A_lo, B_hi, B_lo}, +8 shorts row pad (row
// stride 272 B = 68 dwords = 4 mod 32 banks -> <=2-way conflicts, free).
__global__ __launch_bounds__(256) void gemm_att_hist(const float* __restrict__ x,
                                                     const float* __restrict__ lw,
                                                     const float* __restrict__ att_s,
                                                     const float* __restrict__ att_d,
                                                     const int* __restrict__ ei,
                                                     ushort* __restrict__ xh_bf,
                                                     float* __restrict__ a_src,
                                                     float* __restrict__ a_dst,
                                                     int* __restrict__ cnt) {
  __shared__ __align__(16) ushort AB[4][64][136];   // 69632 B -> 2 blocks/CU
  const int t  = threadIdx.x;
  const int rowBase = blockIdx.x * 64;
  const int colBase = blockIdx.y * 64;
  const int lane = t & 63, wv = t >> 6;

  // degree histogram: 512 edges per block, fire-and-forget, hides under GEMM
  {
    const int bid = blockIdx.y * 128 + blockIdx.x;      // 0..511
    const int gid = bid * 512 + t;
    atomicAdd(&cnt[ei[kE + gid]], 1);                   // ei[1][e] = dst
    atomicAdd(&cnt[ei[kE + gid + 256]], 1);
  }

  f32x4 acc[4] = {};   // 4 col-tiles of 16x16, this wave owns rows wv*16..+15

  for (int kc = 0; kc < 256; kc += 128) {
    __syncthreads();   // previous iteration's reads done before restaging
    // stage 64 rows x 128 k of x and lw, hi/lo split. 2048 float4 slots,
    // thread t does slots t+256*i: r = s>>5, c4 = s&31 (coalesced rows).
#pragma unroll
    for (int i2 = 0; i2 < 8; i2++) {
      const int s = t + 256 * i2;
      const int r = s >> 5, c4 = s & 31;
      float4 xa = *(const float4*)(x  + (long)(rowBase + r) * 256 + kc + c4 * 4);
      float4 ba = *(const float4*)(lw + (long)(colBase + r) * 256 + kc + c4 * 4);
      ushort4 xh4, xl4, bh4, bl4;
      bfsplit(xa.x, xh4.x, xl4.x); bfsplit(xa.y, xh4.y, xl4.y);
      bfsplit(xa.z, xh4.z, xl4.z); bfsplit(xa.w, xh4.w, xl4.w);
      bfsplit(ba.x, bh4.x, bl4.x); bfsplit(ba.y, bh4.y, bl4.y);
      bfsplit(ba.z, bh4.z, bl4.z); bfsplit(ba.w, bh4.w, bl4.w);
      *(ushort4*)&AB[0][r][c4 * 4] = xh4;
      *(ushort4*)&AB[1][r][c4 * 4] = xl4;
      *(ushort4*)&AB[2][r][c4 * 4] = bh4;
      *(ushort4*)&AB[3][r][c4 * 4] = bl4;
    }
    __syncthreads();
    // MFMA: A row = lane&15 (local), k = ks*32 + 8*(lane>>4) + j  (m92 pattern,
    // identical indexing for B -> internal k-permutation cancels)
#pragma unroll
    for (int ks = 0; ks < 4; ks++) {
      const int ko = ks * 32 + ((lane >> 4) << 3);
      bf16x8 ah = *(const bf16x8*)&AB[0][wv * 16 + (lane & 15)][ko];
      bf16x8 al = *(const bf16x8*)&AB[1][wv * 16 + (lane & 15)][ko];
#pragma unroll
      for (int ct = 0; ct < 4; ct++) {
        bf16x8 bh = *(const bf16x8*)&AB[2][ct * 16 + (lane & 15)][ko];
        bf16x8 bl = *(const bf16x8*)&AB[3][ct * 16 + (lane & 15)][ko];
        acc[ct] = __builtin_amdgcn_mfma_f32_16x16x32_bf16(ah, bh, acc[ct], 0, 0, 0);
        acc[ct] = __builtin_amdgcn_mfma_f32_16x16x32_bf16(al, bh, acc[ct], 0, 0, 0);
        acc[ct] = __builtin_amdgcn_mfma_f32_16x16x32_bf16(ah, bl, acc[ct], 0, 0, 0);
      }
    }
  }
  __syncthreads();   // all AB reads done before D aliases over AB[0]

  // D fragment -> LDS (f32 [64][68], 17408 B, exactly overlays AB[0]).
  // D layout (verified m89): col = lane&15, row = (lane>>4)*4 + reg.
  float (*Ds)[68] = reinterpret_cast<float(*)[68]>(&AB[0][0][0]);
#pragma unroll
  for (int ct = 0; ct < 4; ct++)
#pragma unroll
    for (int r = 0; r < 4; r++)
      Ds[wv * 16 + ((lane >> 4) << 2) + r][ct * 16 + (lane & 15)] = acc[ct][r];
  __syncthreads();

  // old proven epilogue, reading Ds in the (tx,ty) 4x4 layout
  const int tx = t & 15, ty = t >> 4;
  float4 as4 = *(const float4*)(att_s + colBase + tx * 4);
  float4 ad4 = *(const float4*)(att_d + colBase + tx * 4);
#pragma unroll
  for (int i = 0; i < 4; i++) {
    const long row = rowBase + ty * 4 + i;
    float4 v = *(const float4*)&Ds[ty * 4 + i][tx * 4];
    ushort4 ob = make_ushort4(f2bf(v.x), f2bf(v.y), f2bf(v.z), f2bf(v.w));
    *(ushort4*)(xh_bf + row * 256 + colBase + tx * 4) = ob;
    float s = v.x * as4.x + v.y * as4.y + v.z * as4.z + v.w * as4.w;
    float d = v.x * ad4.x + v.y * ad4.y + v.z * ad4.z + v.w * ad4.w;
#pragma unroll
    for (int off = 4; off; off >>= 1) {
      s += __shfl_down(s, off, 8);
      d += __shfl_down(d, off, 8);
    }
    if ((tx & 7) == 0) {
      const int head = blockIdx.y * 2 + (tx >> 3);
      a_src[row * 8 + head] = s;
      a_dst[row * 8 + head] = d;
    }
  }
}

// ---------------- K2: single-block exclusive scan (+1 self-loop each) ----------------
// wave-shuffle scan: 16 waves x 64 lanes x 8 elems, 2 barriers total
__global__ __launch_bounds__(1024) void scan_cnt(const int* __restrict__ cnt,
                                                 int* __restrict__ rowptr,
                                                 int* __restrict__ wpos) {
  __shared__ int wsum[16];
  const int t = threadIdx.x, lane = t & 63, w = t >> 6;
  int v[8]; int sum = 0;
#pragma unroll
  for (int q = 0; q < 8; q++) { v[q] = cnt[t * 8 + q] + 1; sum += v[q]; }  // +1 self-loop
  int sc = sum;                                  // inclusive wave scan
#pragma unroll
  for (int off = 1; off < 64; off <<= 1) {
    int n = __shfl_up(sc, off, 64);
    if (lane >= off) sc += n;
  }
  if (lane == 63) wsum[w] = sc;
  __syncthreads();
  if (t < 16) {                                   // scan the 16 wave totals
    int ws = wsum[t];
#pragma unroll
    for (int off = 1; off < 16; off <<= 1) {
      int n = __shfl_up(ws, off, 16);
      if ((t & 15) >= off) ws += n;
    }
    wsum[t] = ws;
  }
  __syncthreads();
  int excl = (w ? wsum[w - 1] : 0) + sc - sum;
#pragma unroll
  for (int q = 0; q < 8; q++) {
    rowptr[t * 8 + q] = excl;
    wpos[t * 8 + q]   = excl;
    excl += v[q];
  }
  if (t == 1023) rowptr[kN] = excl;               // grand total
}

// ---------------- K3: bucket edges by dst + per-edge 8-head weights ----------------
__global__ __launch_bounds__(256) void scatter_csr(const int* __restrict__ ei,
                                                   const float* __restrict__ a_src,
                                                   const float* __restrict__ a_dst,
                                                   int* __restrict__ wpos,
                                                   int* __restrict__ csr,
                                                   float* __restrict__ w8) {
  int idx = blockIdx.x * 256 + threadIdx.x;
  if (idx >= kTotE) return;
  int s, d;
  if (idx < kE) { s = ei[idx]; d = ei[kE + idx]; }
  else          { s = idx - kE; d = s; }
  int pos = atomicAdd(&wpos[d], 1);
  csr[pos] = s;
  float4 s0 = *(const float4*)(a_src + s * 8);
  float4 s1 = *(const float4*)(a_src + s * 8 + 4);
  float4 d0 = *(const float4*)(a_dst + d * 8);
  float4 d1 = *(const float4*)(a_dst + d * 8 + 4);
  float e[8] = {s0.x + d0.x, s0.y + d0.y, s0.z + d0.z, s0.w + d0.w,
                s1.x + d1.x, s1.y + d1.y, s1.z + d1.z, s1.w + d1.w};
  float w[8];
#pragma unroll
  for (int h = 0; h < 8; h++) {
    float ee = (e[h] > 0.f) ? e[h] : 0.2f * e[h];   // leaky_relu(0.2)
    w[h] = __expf(ee);                              // |e| <~ 5, no max-sub needed
  }
  float4* wp = (float4*)(w8 + (long)pos * 8);
  wp[0] = make_float4(w[0], w[1], w[2], w[3]);
  wp[1] = make_float4(w[4], w[5], w[6], w[7]);
}

// ---------- K4: fused weighted-gather aggregation + final dot ----------
// Block = dst node i. Phase 0 issues the 8 nt out_w loads (independent of the
// gather). Phase 1 gathers bf16 rows + w8, predicated unroll-8 (no serial
// tail; OOB lanes re-read edge j with weight zero-selected). Phase 2 exchanges
// the of-row via LDS, 32 channel dots, bucketed atomics into ypart.
__global__ __launch_bounds__(256) void agg_dot(const ushort* __restrict__ xb,
                                               const float* __restrict__ w8,
                                               const int* __restrict__ rowptr,
                                               const int* __restrict__ csr,
                                               const float* __restrict__ bias,
                                               const float* __restrict__ w,
                                               float* __restrict__ ypart) {
  const int i = blockIdx.x, t = threadIdx.x, h = t >> 5;
  const int lane = t & 63, wid = t >> 6;

  const int beg = rowptr[i], end = rowptr[i + 1];

  // phase 0: prefetch this node's out_w slice — w[c][i*256 + lane*4], c = cc*4+wid
  const long wbase = (long)i * 256 + lane * 4;
  vfloat4 wv[8];
#pragma unroll
  for (int cc = 0; cc < 8; cc++) {
    const int c = cc * 4 + wid;
    wv[cc] = __builtin_nontemporal_load((const vfloat4*)(w + (long)c * kK + wbase));
  }

  // phase 1: gather aggregation, predicated unroll x8
  float acc = 0.f, den = 0.f;
  for (int j = beg; j < end; j += 8) {
    const int lim = end - j;            // >= 1
    int s[8]; float ww[8]; float f[8];
#pragma unroll
    for (int q = 0; q < 8; q++) {
      const int jj = (q < lim) ? j + q : j;
      s[q]  = csr[jj];
      ww[q] = w8[(long)jj * 8 + h];
    }
#pragma unroll
    for (int q = 0; q < 8; q++) f[q] = bf2f(xb[(long)s[q] * 256 + t]);
#pragma unroll
    for (int q = 0; q < 8; q++) {
      const float wq = (q < lim) ? ww[q] : 0.f;
      den += wq;
      acc += wq * f[q];
    }
  }

  // phase 2: of-row through LDS, 32 per-block dots, wave reduce, bucket atomics
  __shared__ float ofs[256];
  __shared__ float yb[32];
  ofs[t] = acc / den + bias[t];
  __syncthreads();
  float4 f4 = *(const float4*)(ofs + lane * 4);
#pragma unroll
  for (int cc = 0; cc < 8; cc++) {
    float p = wv[cc].x * f4.x + wv[cc].y * f4.y + wv[cc].z * f4.z + wv[cc].w * f4.w;
    p += __shfl_down(p, 32, 64);
    p += __shfl_down(p, 16, 64);
    p += __shfl_down(p, 8, 64);
    p += __shfl_down(p, 4, 64);
    p += __shfl_down(p, 2, 64);
    p += __shfl_down(p, 1, 64);
    if (lane == 0) yb[cc * 4 + wid] = p;
  }
  __syncthreads();
  if (t < 32) atomicAdd(&ypart[(i & (kYB - 1)) * 32 + t], yb[t]);
}

// ---------------- K5: reduce ypart[256][32] + bias + softmax ----------------
__global__ __launch_bounds__(1024) void finalize(const float* __restrict__ ypart,
                                                 const float* __restrict__ ob,
                                                 float* __restrict__ out) {
  __shared__ float s[32][33];
  const int t = threadIdx.x;
  const int c = t & 31, r = t >> 5;
  float sum = 0.f;
  for (int q = r; q < kYB; q += 32) sum += ypart[q * 32 + c];  // 8 adds per thread
  s[c][r] = sum;
  __syncthreads();
  if (t < 32) {
    float y = ob[t];
#pragma unroll
    for (int r2 = 0; r2 < 32; r2++) y += s[t][r2];
    float m = y;
#pragma unroll
    for (int off = 16; off; off >>= 1) m = fmaxf(m, __shfl_xor(m, off, 32));
    float e = __expf(y - m);
    float d = e;
#pragma unroll
    for (int off = 16; off; off >>= 1) d += __shfl_xor(d, off, 32);
    out[t] = e / d;
  }
}

extern "C" void kernel_launch(void* const* d_in, const int* in_sizes, int n_in,
                              void* d_out, int out_size, void* d_ws, size_t ws_size,
                              hipStream_t stream) {
  (void)in_sizes; (void)n_in; (void)out_size; (void)ws_size;
  const float* x     = (const float*)d_in[0];
  const int*   ei    = (const int*)  d_in[1];
  const float* lin_w = (const float*)d_in[2];
  const float* att_s = (const float*)d_in[3];
  const float* att_d = (const float*)d_in[4];
  const float* bias  = (const float*)d_in[5];
  const float* out_w = (const float*)d_in[6];
  const float* out_b = (const float*)d_in[7];
  float* out = (float*)d_out;

  // workspace layout (~15 MB)
  float*  a_src    = (float*)d_ws;
  float*  a_dst    = a_src + kN * 8;
  float*  w8       = a_dst + kN * 8;
  ushort* xh_bf    = (ushort*)(w8 + (long)kTotE * 8);
  int*    cnt      = (int*)(xh_bf + kK);
  float*  ypart    = (float*)(cnt + kN);          // kYB*32 floats, adjacent to cnt
  int*    rowptr   = (int*)(ypart + kYB * 32);
  int*    wpos     = rowptr + (kN + 1);
  int*    csr      = wpos + kN;

  // zero cnt + ypart in one memset (adjacent)
  (void)hipMemsetAsync(cnt, 0, kN * sizeof(int) + kYB * 32 * sizeof(float), stream);
  gemm_att_hist<<<dim3(128, 4), 256, 0, stream>>>(x, lin_w, att_s, att_d, ei,
                                                  xh_bf, a_src, a_dst, cnt);
  scan_cnt   <<<1, 1024, 0, stream>>>(cnt, rowptr, wpos);
  scatter_csr<<<(kTotE + 255) / 256, 256, 0, stream>>>(ei, a_src, a_dst, wpos, csr, w8);
  agg_dot    <<<kN, 256, 0, stream>>>(xh_bf, w8, rowptr, csr, bias, out_w, ypart);
  finalize   <<<1, 1024, 0, stream>>>(ypart, out_b, out);
}